// Round 10
// baseline (199.579 us; speedup 1.0000x reference)
//
#include <hip/hip_runtime.h>

#define INV_N (1.0f / 4096.0f)

__device__ __forceinline__ void bf(float& ar, float& ai, float& br, float& bi,
                                   float s, float cs) {
    float tr = cs * br - s * bi;
    float ti = cs * bi + s * br;
    br = ar - tr; bi = ai - ti;
    ar = ar + tr; ai = ai + ti;
}

// Twiddle: angle = -2pi*(k/4096)*wk radians => rev = -(k/4096)*wk revolutions.
__device__ __forceinline__ void tw(int k, float wk, float* s, float* cs) {
    float rev = (float)k * (-INV_N) * wk;
    rev = __builtin_amdgcn_fractf(rev);          // [0,1), handles negatives
    *s  = __builtin_amdgcn_sinf(rev);            // sin(2*pi*rev)
    *cs = __builtin_amdgcn_cosf(rev);            // cos(2*pi*rev)
}

// Raw barrier with LDS-only drain. __syncthreads() makes the compiler emit
// "s_waitcnt vmcnt(0) lgkmcnt(0)" before s_barrier, draining the ENTIRE
// global-load queue at every exchange barrier — which nullified all load/
// compute overlap in R7-R9. The exchange only needs each wave's own LDS ops
// retired (lgkmcnt(0)); in-flight global loads legally ride through.
#define BAR() do { asm volatile("s_waitcnt lgkmcnt(0)" ::: "memory"); \
                   __builtin_amdgcn_s_barrier(); } while (0)

// Two-round 16 KB ownership exchange: consecutive-16 rows -> stride-4 rows.
// Parity predicate (pb + (m>>2) + (m&3)) & 1: what a thread flushes in a
// round is exactly what it refills in that round (no extra live VGPRs).
// All 3 barriers are raw (vmcnt queue stays live).
__device__ __forceinline__ void exchange(float2* tile, float (&ar)[16],
                                         float (&ai)[16], int pb, int c) {
#pragma unroll
    for (int par = 0; par < 2; ++par) {
#pragma unroll
        for (int m = 0; m < 16; ++m) {
            if (((pb + (m >> 2) + (m & 3)) & 1) == par) {
                int srow = (pb << 3) + (((m >> 2) << 1) | ((m & 3) >> 1));
                tile[srow * 64 + c] = make_float2(ar[m], ai[m]);
            }
        }
        BAR();
#pragma unroll
        for (int m = 0; m < 16; ++m) {
            if (((pb + (m >> 2) + (m & 3)) & 1) == par) {
                int srow = ((m >> 2) << 3) + ((m & 3) << 1) + (pb >> 1);
                float2 v = tile[srow * 64 + c];
                ar[m] = v.x; ai[m] = v.y;
            }
        }
        if (par == 0) BAR();
    }
}

// Kernel A: stages step=2..64. Two-half pipeline (R9) + raw-barrier exchange.
// Issue order: rows0-7, even-s1 w, rows8-15, odd-s1 w, phase-2 w. Phase-2
// twiddles are computed AFTER the exchange so the 12 tail w-loads stay in
// flight through the 3 barriers + 64 LDS ops.
__global__ __launch_bounds__(256) void fft_lo(const float* __restrict__ x,
                                              const float* __restrict__ w,
                                              float2* __restrict__ dst2,
                                              unsigned dst_lim2) {
    __shared__ __align__(16) float2 tile[32 * 64];   // 16 KB, exchange only
    const int t   = threadIdx.x;
    const int c   = t & 63;
    const int pb  = t >> 6;
    const int c0  = (blockIdx.x & 63) << 6;
    const int r0  = (blockIdx.x >> 6) << 6;
    const int src_r0 = r0 ^ 2048;      // initial permutation: new[i] = old[i^2048]
    const unsigned col = (unsigned)(c0 + c);

    float ar[16], ai[16];
    // ---- 1) data rows 0..7 ----
#pragma unroll
    for (int m = 0; m < 8; ++m) {
        unsigned gi = (unsigned)(src_r0 + 16 * pb + m) * 4096u + col;
        ar[m] = __builtin_nontemporal_load(&x[gi]);
        ai[m] = 0.f;
    }
    // ---- 2) w for half-stage twiddles s1[2],s1[4],s1[6] (k=512,1024,1536) ----
    float wpe[3];
#pragma unroll
    for (int i = 0; i < 3; ++i)
        wpe[i] = w[(unsigned)(512 * (i + 1)) * 4096u + col];
    // ---- 3) data rows 8..15 ----
#pragma unroll
    for (int m = 8; m < 16; ++m) {
        unsigned gi = (unsigned)(src_r0 + 16 * pb + m) * 4096u + col;
        ar[m] = __builtin_nontemporal_load(&x[gi]);
        ai[m] = 0.f;
    }
    // ---- 4) w for cross-stage twiddles s1[1,3,5,7] (k=256,768,1280,1792) ----
    float wpo[4];
#pragma unroll
    for (int i = 0; i < 4; ++i)
        wpo[i] = w[(unsigned)(256 * (2 * i + 1)) * 4096u + col];
    // ---- 5) phase-2 w LAST (12 loads; ride through the exchange) ----
    float w2a[4], w2b[8];
#pragma unroll
    for (int i = 0; i < 4; ++i)
        w2a[i] = w[(unsigned)((pb + 4 * i) * 128) * 4096u + col];
#pragma unroll
    for (int i = 0; i < 8; ++i)
        w2b[i] = w[(unsigned)((pb + 4 * i) * 64) * 4096u + col];

    // ---- even twiddles (gate: rows0-7 + wpe = 11 loads) ----
    float s1[8], c1[8];
    s1[0] = 0.f; c1[0] = 1.f;
    tw(512,  wpe[0], &s1[2], &c1[2]);
    tw(1024, wpe[1], &s1[4], &c1[4]);
    tw(1536, wpe[2], &s1[6], &c1[6]);

    // ---- half stages h=1,2,4 on each half ----
#pragma unroll
    for (int base = 0; base <= 8; base += 8) {
#pragma unroll
        for (int b = 0; b < 4; ++b)          // h=1, identity
            bf(ar[base + 2 * b], ai[base + 2 * b],
               ar[base + 2 * b + 1], ai[base + 2 * b + 1], 0.f, 1.f);
#pragma unroll
        for (int r = 0; r < 2; ++r)          // h=2, ti=4r
#pragma unroll
            for (int b = 0; b < 2; ++b) {
                int mt = base + b * 4 + r;
                bf(ar[mt], ai[mt], ar[mt + 2], ai[mt + 2], s1[4 * r], c1[4 * r]);
            }
#pragma unroll
        for (int r = 0; r < 4; ++r) {        // h=4, ti=2r
            int mt = base + r;
            bf(ar[mt], ai[mt], ar[mt + 4], ai[mt + 4], s1[2 * r], c1[2 * r]);
        }
    }

    // ---- odd twiddles then cross stage h=8 ----
    tw(256,  wpo[0], &s1[1], &c1[1]);
    tw(768,  wpo[1], &s1[3], &c1[3]);
    tw(1280, wpo[2], &s1[5], &c1[5]);
    tw(1792, wpo[3], &s1[7], &c1[7]);
#pragma unroll
    for (int r = 0; r < 8; ++r)
        bf(ar[r], ai[r], ar[r + 8], ai[r + 8], s1[r], c1[r]);

    // ---- ownership exchange (raw barriers; w2 loads still in flight) ----
    exchange(tile, ar, ai, pb, c);

    // ---- phase-2 twiddles AFTER exchange (w2 had max time to drain) ----
    float s2a[4], c2a[4], s2b[8], c2b[8];
#pragma unroll
    for (int i = 0; i < 4; ++i)
        tw((pb + 4 * i) * 128, w2a[i], &s2a[i], &c2a[i]);
#pragma unroll
    for (int i = 0; i < 8; ++i)
        tw((pb + 4 * i) * 64, w2b[i], &s2b[i], &c2b[i]);

    // ---- phase 2: step 32 (pairs m,m+4) then step 64 (pairs m,m+8) ----
#pragma unroll
    for (int rm = 0; rm < 4; ++rm) {
#pragma unroll
        for (int b = 0; b < 2; ++b) {
            const int mt = b * 8 + rm;
            bf(ar[mt], ai[mt], ar[mt + 4], ai[mt + 4], s2a[rm], c2a[rm]);
        }
    }
#pragma unroll
    for (int m = 0; m < 8; ++m)
        bf(ar[m], ai[m], ar[m + 8], ai[m + 8], s2b[m], c2b[m]);

    // ---- direct stores: rows r0 + pb + 4*m ----
#pragma unroll
    for (int m = 0; m < 16; ++m) {
        unsigned gi = (unsigned)(r0 + pb + 4 * m) * 4096u + col;
        if (gi < dst_lim2) dst2[gi] = make_float2(ar[m], ai[m]);
    }
}

// Kernel B: stages step=128..4096. Same structure: raw-barrier exchange +
// post-exchange phase-2 twiddles.
template <int REAL_OUT>
__global__ __launch_bounds__(256) void fft_hi(const float* __restrict__ w,
                                              const float2* __restrict__ src2,
                                              float2* __restrict__ dstc,
                                              float* __restrict__ dstr,
                                              unsigned dst_lim) {
    __shared__ __align__(16) float2 tile[32 * 64];   // 16 KB, exchange only
    const int t    = threadIdx.x;
    const int c    = t & 63;
    const int pb   = t >> 6;
    const int rres = blockIdx.x >> 6;
    const unsigned col = (unsigned)(((blockIdx.x & 63) << 6) + c);

    float ar[16], ai[16];
    // ---- 1) data rows 0..7 ----
#pragma unroll
    for (int m = 0; m < 8; ++m) {
        unsigned gi = (unsigned)(rres + 64 * (16 * pb + m)) * 4096u + col;
        float2 v = src2[gi];
        ar[m] = v.x; ai[m] = v.y;
    }
    // ---- 2) w for half stages h=1,2,4 (7 loads) ----
    float wp1, wp2[2], wp4[4];
    wp1 = w[(unsigned)(rres * 32) * 4096u + col];
#pragma unroll
    for (int r = 0; r < 2; ++r)
        wp2[r] = w[(unsigned)((rres + 64 * r) * 16) * 4096u + col];
#pragma unroll
    for (int r = 0; r < 4; ++r)
        wp4[r] = w[(unsigned)((rres + 64 * r) * 8) * 4096u + col];
    // ---- 3) data rows 8..15 ----
#pragma unroll
    for (int m = 8; m < 16; ++m) {
        unsigned gi = (unsigned)(rres + 64 * (16 * pb + m)) * 4096u + col;
        float2 v = src2[gi];
        ar[m] = v.x; ai[m] = v.y;
    }
    // ---- 4) w for cross stage h=8 (8 loads) ----
    float wp8[8];
#pragma unroll
    for (int r = 0; r < 8; ++r)
        wp8[r] = w[(unsigned)((rres + 64 * r) * 4) * 4096u + col];
    // ---- 5) phase-2 w LAST (12 loads; ride through the exchange) ----
    float w2a[4], w2b[8];
#pragma unroll
    for (int i = 0; i < 4; ++i)
        w2a[i] = w[(unsigned)((rres + 64 * (pb + 4 * i)) * 2) * 4096u + col];
#pragma unroll
    for (int i = 0; i < 8; ++i)
        w2b[i] = w[(unsigned)(rres + 64 * (pb + 4 * i)) * 4096u + col];

    // ---- half-stage twiddles (gate: rows0-7 + 7 w = 15 of 43 loads) ----
    float st1, ct1, st2[2], ct2[2], st4[4], ct4[4];
    tw(rres * 32, wp1, &st1, &ct1);
#pragma unroll
    for (int r = 0; r < 2; ++r)
        tw((rres + 64 * r) * 16, wp2[r], &st2[r], &ct2[r]);
#pragma unroll
    for (int r = 0; r < 4; ++r)
        tw((rres + 64 * r) * 8, wp4[r], &st4[r], &ct4[r]);

    // ---- half stages h=1,2,4 on each half ----
#pragma unroll
    for (int base = 0; base <= 8; base += 8) {
#pragma unroll
        for (int b = 0; b < 4; ++b)          // h=1 (global step 128)
            bf(ar[base + 2 * b], ai[base + 2 * b],
               ar[base + 2 * b + 1], ai[base + 2 * b + 1], st1, ct1);
#pragma unroll
        for (int r = 0; r < 2; ++r)          // h=2 (step 256)
#pragma unroll
            for (int b = 0; b < 2; ++b) {
                int mt = base + b * 4 + r;
                bf(ar[mt], ai[mt], ar[mt + 2], ai[mt + 2], st2[r], ct2[r]);
            }
#pragma unroll
        for (int r = 0; r < 4; ++r) {        // h=4 (step 512)
            int mt = base + r;
            bf(ar[mt], ai[mt], ar[mt + 4], ai[mt + 4], st4[r], ct4[r]);
        }
    }

    // ---- cross-stage twiddles then h=8 (global step 1024) ----
#pragma unroll
    for (int r = 0; r < 8; ++r) {
        float s, cs;
        tw((rres + 64 * r) * 4, wp8[r], &s, &cs);
        bf(ar[r], ai[r], ar[r + 8], ai[r + 8], s, cs);
    }

    // ---- ownership exchange (raw barriers; w2 loads still in flight) ----
    exchange(tile, ar, ai, pb, c);

    // ---- phase-2 twiddles AFTER exchange ----
    float s2a[4], c2a[4], s2b[8], c2b[8];
#pragma unroll
    for (int i = 0; i < 4; ++i)
        tw((rres + 64 * (pb + 4 * i)) * 2, w2a[i], &s2a[i], &c2a[i]);
#pragma unroll
    for (int i = 0; i < 8; ++i)
        tw(rres + 64 * (pb + 4 * i), w2b[i], &s2b[i], &c2b[i]);

    // ---- phase 2: global steps 2048 (m,m+4) and 4096 (m,m+8) ----
#pragma unroll
    for (int rm = 0; rm < 4; ++rm) {
#pragma unroll
        for (int b = 0; b < 2; ++b) {
            const int mt = b * 8 + rm;
            bf(ar[mt], ai[mt], ar[mt + 4], ai[mt + 4], s2a[rm], c2a[rm]);
        }
    }
#pragma unroll
    for (int m = 0; m < 8; ++m)
        bf(ar[m], ai[m], ar[m + 8], ai[m + 8], s2b[m], c2b[m]);

    // ---- stores: rows rres + 64*(pb+4*m), row-major output ----
    if (REAL_OUT) {
#pragma unroll
        for (int m = 0; m < 16; ++m) {
            unsigned gi = (unsigned)(rres + 64 * (pb + 4 * m)) * 4096u + col;
            if (gi < dst_lim) __builtin_nontemporal_store(ar[m], &dstr[gi]);
        }
    } else {
#pragma unroll
        for (int m = 0; m < 16; ++m) {
            unsigned gi = (unsigned)(rres + 64 * (pb + 4 * m)) * 4096u + col;
            if (gi < dst_lim) dstc[gi] = make_float2(ar[m], ai[m]);
        }
    }
}

extern "C" void kernel_launch(void* const* d_in, const int* in_sizes, int n_in,
                              void* d_out, int out_size, void* d_ws, size_t ws_size,
                              hipStream_t stream) {
    const float* x = (const float*)d_in[0];
    const float* w = (const float*)d_in[1];
    const long long NN = 4096LL * 4096LL;

    if ((long long)out_size >= 2 * NN) {
        // d_out = interleaved complex (2*N*N floats): compute in-place.
        float2* o2 = (float2*)d_out;
        unsigned lim2 = (unsigned)(out_size / 2);          // float2 units
        fft_lo<<<4096, 256, 0, stream>>>(x, w, o2, lim2);
        fft_hi<0><<<4096, 256, 0, stream>>>(w, o2, o2, nullptr, lim2);
    } else {
        // Confirmed world: d_out = N*N floats (real part). Complex
        // intermediate in d_ws (>= 2*N*N floats, verified earlier rounds).
        float2* ws2 = (float2*)d_ws;
        unsigned ws_lim2 = (unsigned)(ws_size / 8);        // bytes -> float2 units
        unsigned out_lim = (unsigned)out_size;             // float units
        fft_lo<<<4096, 256, 0, stream>>>(x, w, ws2, ws_lim2);
        fft_hi<1><<<4096, 256, 0, stream>>>(w, (const float2*)ws2, nullptr,
                                            (float*)d_out, out_lim);
    }
}